// Round 2
// baseline (79.255 us; speedup 1.0000x reference)
//
#include <hip/hip_runtime.h>
#include <math.h>

#define EPS 1e-6f

// 4 points per thread: pos/out rows are 12B, so groups of 4 points make
// 48B = 3 x float4 fully-coalesced accesses; net rows are 48B = 3 x float4.
__global__ __launch_bounds__(256) void deform_kernel4(
    const float* __restrict__ pos,   // (N,3)
    const float* __restrict__ net,   // (N,12)
    float* __restrict__ out,         // (N,3)
    int ngroups)                     // N/4
{
    int t = blockIdx.x * blockDim.x + threadIdx.x;
    if (t >= ngroups) return;

    const float4* pos4 = reinterpret_cast<const float4*>(pos);
    const float4* net4 = reinterpret_cast<const float4*>(net);
    float4* out4 = reinterpret_cast<float4*>(out);

    float4 q0 = pos4[t * 3 + 0];
    float4 q1 = pos4[t * 3 + 1];
    float4 q2 = pos4[t * 3 + 2];

    float xs[4][3] = {{q0.x, q0.y, q0.z},
                      {q0.w, q1.x, q1.y},
                      {q1.z, q1.w, q2.x},
                      {q2.y, q2.z, q2.w}};
    float os[4][3];

#pragma unroll
    for (int k = 0; k < 4; ++k) {
        float4 a = net4[t * 12 + k * 3 + 0];  // wx wy wz vx
        float4 b = net4[t * 12 + k * 3 + 1];  // vy vz px py
        float4 c = net4[t * 12 + k * 3 + 2];  // pz tx ty tz

        float wx = a.x, wy = a.y, wz = a.z;
        float vx = a.w, vy = b.x, vz = b.y;
        float px = b.z, py = b.w, pz = c.x;
        float tx = c.y, ty = c.z, tz = c.w;

        float theta = sqrtf(wx * wx + wy * wy + wz * wz) + EPS;
        float inv = 1.0f / theta;
        wx *= inv; wy *= inv; wz *= inv;
        vx *= inv; vy *= inv; vz *= inv;

        float s, co;
        sincosf(theta, &s, &co);
        float c1 = 1.0f - co;     // 1 - cos(theta)
        float c2 = theta - s;     // theta - sin(theta)

        // p = theta*v + c1*(w x v) + c2*(w x (w x v))
        float cvx = wy * vz - wz * vy;
        float cvy = wz * vx - wx * vz;
        float cvz = wx * vy - wy * vx;
        float ccvx = wy * cvz - wz * cvy;
        float ccvy = wz * cvx - wx * cvz;
        float ccvz = wx * cvy - wy * cvx;
        float p0 = theta * vx + c1 * cvx + c2 * ccvx;
        float p1 = theta * vy + c1 * cvy + c2 * ccvy;
        float p2 = theta * vz + c1 * cvz + c2 * ccvz;

        // r = x + pivot
        float r0 = xs[k][0] + px;
        float r1 = xs[k][1] + py;
        float r2 = xs[k][2] + pz;

        // offset = (exp_so3@r) - r + p + t  =  s*(w x r) + c1*(w x (w x r)) + p + t
        float crx = wy * r2 - wz * r1;
        float cry = wz * r0 - wx * r2;
        float crz = wx * r1 - wy * r0;
        float ccrx = wy * crz - wz * cry;
        float ccry = wz * crx - wx * crz;
        float ccrz = wx * cry - wy * crx;

        os[k][0] = s * crx + c1 * ccrx + p0 + tx;
        os[k][1] = s * cry + c1 * ccry + p1 + ty;
        os[k][2] = s * crz + c1 * ccrz + p2 + tz;
    }

    out4[t * 3 + 0] = make_float4(os[0][0], os[0][1], os[0][2], os[1][0]);
    out4[t * 3 + 1] = make_float4(os[1][1], os[1][2], os[2][0], os[2][1]);
    out4[t * 3 + 2] = make_float4(os[2][2], os[3][0], os[3][1], os[3][2]);
}

extern "C" void kernel_launch(void* const* d_in, const int* in_sizes, int n_in,
                              void* d_out, int out_size, void* d_ws, size_t ws_size,
                              hipStream_t stream) {
    const float* pos = (const float*)d_in[0];   // undeformed_positions (N,3)
    const float* net = (const float*)d_in[1];   // network_output (N,12)
    float* out = (float*)d_out;                 // offsets (N,3)
    int n = in_sizes[0] / 3;                    // N points (divisible by 4: N = 2^22)
    int ngroups = n / 4;

    int block = 256;
    int grid = (ngroups + block - 1) / block;
    deform_kernel4<<<grid, block, 0, stream>>>(pos, net, out, ngroups);
}

// Round 3
// 78.871 us; speedup vs baseline: 1.0049x; 1.0049x over previous
//
#include <hip/hip_runtime.h>
#include <math.h>

#define EPS 1e-6f

// 4 points per thread: pos/out rows are 12B, so groups of 4 points make
// 48B = 3 x float4 fully-coalesced accesses; net rows are 48B = 3 x float4.
__global__ __launch_bounds__(256) void deform_kernel4(
    const float* __restrict__ pos,   // (N,3)
    const float* __restrict__ net,   // (N,12)
    float* __restrict__ out,         // (N,3)
    int ngroups)                     // N/4
{
    int t = blockIdx.x * blockDim.x + threadIdx.x;
    if (t >= ngroups) return;

    const float4* pos4 = reinterpret_cast<const float4*>(pos);
    const float4* net4 = reinterpret_cast<const float4*>(net);
    float4* out4 = reinterpret_cast<float4*>(out);

    float4 q0 = pos4[t * 3 + 0];
    float4 q1 = pos4[t * 3 + 1];
    float4 q2 = pos4[t * 3 + 2];

    float xs[4][3] = {{q0.x, q0.y, q0.z},
                      {q0.w, q1.x, q1.y},
                      {q1.z, q1.w, q2.x},
                      {q2.y, q2.z, q2.w}};
    float os[4][3];

#pragma unroll
    for (int k = 0; k < 4; ++k) {
        float4 a = net4[t * 12 + k * 3 + 0];  // wx wy wz vx
        float4 b = net4[t * 12 + k * 3 + 1];  // vy vz px py
        float4 c = net4[t * 12 + k * 3 + 2];  // pz tx ty tz

        float wx = a.x, wy = a.y, wz = a.z;
        float vx = a.w, vy = b.x, vz = b.y;
        float px = b.z, py = b.w, pz = c.x;
        float tx = c.y, ty = c.z, tz = c.w;

        float theta = sqrtf(wx * wx + wy * wy + wz * wz) + EPS;
        float inv = 1.0f / theta;
        wx *= inv; wy *= inv; wz *= inv;
        vx *= inv; vy *= inv; vz *= inv;

        float s, co;
        sincosf(theta, &s, &co);
        float c1 = 1.0f - co;     // 1 - cos(theta)
        float c2 = theta - s;     // theta - sin(theta)

        // p = theta*v + c1*(w x v) + c2*(w x (w x v))
        float cvx = wy * vz - wz * vy;
        float cvy = wz * vx - wx * vz;
        float cvz = wx * vy - wy * vx;
        float ccvx = wy * cvz - wz * cvy;
        float ccvy = wz * cvx - wx * cvz;
        float ccvz = wx * cvy - wy * cvx;
        float p0 = theta * vx + c1 * cvx + c2 * ccvx;
        float p1 = theta * vy + c1 * cvy + c2 * ccvy;
        float p2 = theta * vz + c1 * cvz + c2 * ccvz;

        // r = x + pivot
        float r0 = xs[k][0] + px;
        float r1 = xs[k][1] + py;
        float r2 = xs[k][2] + pz;

        // offset = (exp_so3@r) - r + p + t  =  s*(w x r) + c1*(w x (w x r)) + p + t
        float crx = wy * r2 - wz * r1;
        float cry = wz * r0 - wx * r2;
        float crz = wx * r1 - wy * r0;
        float ccrx = wy * crz - wz * cry;
        float ccry = wz * crx - wx * crz;
        float ccrz = wx * cry - wy * crx;

        os[k][0] = s * crx + c1 * ccrx + p0 + tx;
        os[k][1] = s * cry + c1 * ccry + p1 + ty;
        os[k][2] = s * crz + c1 * ccrz + p2 + tz;
    }

    out4[t * 3 + 0] = make_float4(os[0][0], os[0][1], os[0][2], os[1][0]);
    out4[t * 3 + 1] = make_float4(os[1][1], os[1][2], os[2][0], os[2][1]);
    out4[t * 3 + 2] = make_float4(os[2][2], os[3][0], os[3][1], os[3][2]);
}

extern "C" void kernel_launch(void* const* d_in, const int* in_sizes, int n_in,
                              void* d_out, int out_size, void* d_ws, size_t ws_size,
                              hipStream_t stream) {
    const float* pos = (const float*)d_in[0];   // undeformed_positions (N,3)
    const float* net = (const float*)d_in[1];   // network_output (N,12)
    float* out = (float*)d_out;                 // offsets (N,3)
    int n = in_sizes[0] / 3;                    // N points (divisible by 4: N = 2^22)
    int ngroups = n / 4;

    int block = 256;
    int grid = (ngroups + block - 1) / block;
    deform_kernel4<<<grid, block, 0, stream>>>(pos, net, out, ngroups);
}

// Round 4
// 52.154 us; speedup vs baseline: 1.5196x; 1.5123x over previous
//
#include <hip/hip_runtime.h>
#include <math.h>

#define EPS 1e-6f
#define PAD 13   // padded row stride (floats) for net panel: gcd(13,32)=1 -> conflict-free reads

// One point per thread. Per block of 256 threads:
//   phase 1: load the block's net panel (256 rows x 48B = 12KB) with perfectly
//            dense float4 loads (lane stride 16B), scatter into LDS rows padded
//            to 13 floats.
//   phase 2: each thread reads its 12 floats from LDS (2 lanes/bank = free),
//            pos via direct scalar loads (12B stride), compute, scalar stores.
__global__ __launch_bounds__(256) void deform_staged(
    const float* __restrict__ pos,   // (N,3)
    const float* __restrict__ net,   // (N,12)
    float* __restrict__ out,         // (N,3)
    int n)
{
    __shared__ float net_lds[256 * PAD];  // 13312 B

    const int tid = threadIdx.x;
    const int blockBase = blockIdx.x * 256;
    const int i = blockBase + tid;

    // Issue pos loads early (independent of LDS staging).
    float x0 = 0.f, x1 = 0.f, x2 = 0.f;
    if (i < n) {
        x0 = pos[i * 3 + 0];
        x1 = pos[i * 3 + 1];
        x2 = pos[i * 3 + 2];
    }

    // Phase 1: dense global -> LDS (padded scatter).
    const float4* net4 = reinterpret_cast<const float4*>(net) + (size_t)blockBase * 3;
#pragma unroll
    for (int j = 0; j < 3; ++j) {
        int idx4 = tid + j * 256;             // float4 index within block panel (0..767)
        if (blockBase + (idx4 * 4) / 12 < n) {  // guard (always true for N=2^22)
            float4 v = net4[idx4];
            float vv[4] = {v.x, v.y, v.z, v.w};
            int g = idx4 * 4;                 // float index within panel
#pragma unroll
            for (int e = 0; e < 4; ++e) {
                int ge = g + e;
                int row = ge / 12;            // magic-mul, compile-time constant divisor
                int col = ge - row * 12;
                net_lds[row * PAD + col] = vv[e];
            }
        }
    }
    __syncthreads();

    if (i >= n) return;

    // Phase 2: per-thread row read from LDS (conflict-free: stride 13).
    const float* r = &net_lds[tid * PAD];
    float wx = r[0], wy = r[1], wz = r[2];
    float vx = r[3], vy = r[4], vz = r[5];
    float px = r[6], py = r[7], pz = r[8];
    float tx = r[9], ty = r[10], tz = r[11];

    float theta = sqrtf(wx * wx + wy * wy + wz * wz) + EPS;
    float inv = 1.0f / theta;
    wx *= inv; wy *= inv; wz *= inv;
    vx *= inv; vy *= inv; vz *= inv;

    float s, co;
    sincosf(theta, &s, &co);
    float c1 = 1.0f - co;     // 1 - cos(theta)
    float c2 = theta - s;     // theta - sin(theta)

    // p = theta*v + c1*(w x v) + c2*(w x (w x v))
    float cvx = wy * vz - wz * vy;
    float cvy = wz * vx - wx * vz;
    float cvz = wx * vy - wy * vx;
    float ccvx = wy * cvz - wz * cvy;
    float ccvy = wz * cvx - wx * cvz;
    float ccvz = wx * cvy - wy * cvx;
    float p0 = theta * vx + c1 * cvx + c2 * ccvx;
    float p1 = theta * vy + c1 * cvy + c2 * ccvy;
    float p2 = theta * vz + c1 * cvz + c2 * ccvz;

    // r = x + pivot
    float r0 = x0 + px, r1 = x1 + py, r2 = x2 + pz;

    // offset = s*(w x r) + c1*(w x (w x r)) + p + t
    float crx = wy * r2 - wz * r1;
    float cry = wz * r0 - wx * r2;
    float crz = wx * r1 - wy * r0;
    float ccrx = wy * crz - wz * cry;
    float ccry = wz * crx - wx * crz;
    float ccrz = wx * cry - wy * crx;

    out[i * 3 + 0] = s * crx + c1 * ccrx + p0 + tx;
    out[i * 3 + 1] = s * cry + c1 * ccry + p1 + ty;
    out[i * 3 + 2] = s * crz + c1 * ccrz + p2 + tz;
}

extern "C" void kernel_launch(void* const* d_in, const int* in_sizes, int n_in,
                              void* d_out, int out_size, void* d_ws, size_t ws_size,
                              hipStream_t stream) {
    const float* pos = (const float*)d_in[0];   // undeformed_positions (N,3)
    const float* net = (const float*)d_in[1];   // network_output (N,12)
    float* out = (float*)d_out;                 // offsets (N,3)
    int n = in_sizes[0] / 3;                    // N points

    int block = 256;
    int grid = (n + block - 1) / block;
    deform_staged<<<grid, block, 0, stream>>>(pos, net, out, n);
}